// Round 2
// baseline (317.529 us; speedup 1.0000x reference)
//
#include <hip/hip_runtime.h>

#define SDIM 2048
#define DDIM 512
#define NB 8

typedef __bf16 bf16x8 __attribute__((ext_vector_type(8)));
typedef float f32x4 __attribute__((ext_vector_type(4)));

__device__ __forceinline__ ushort f2bf(float f) {
  unsigned u = __float_as_uint(f);
  u = (u + 0x7FFFu + ((u >> 16) & 1u)) >> 16;  // RNE
  return (ushort)u;
}

// ---- prepass: K fp32 -> bf16 ----
__global__ void convert_k(const float* __restrict__ K, ushort* __restrict__ Kb) {
  const long N4 = (long)NB * SDIM * DDIM / 4;
  const long stride = (long)gridDim.x * blockDim.x;
  for (long i = (long)blockIdx.x * blockDim.x + threadIdx.x; i < N4; i += stride) {
    float4 k = ((const float4*)K)[i];
    ushort4 o;
    o.x = f2bf(k.x); o.y = f2bf(k.y); o.z = f2bf(k.z); o.w = f2bf(k.w);
    ((ushort4*)Kb)[i] = o;
  }
}

// ---- prepass: V fp32 [b][s][d] -> bf16 V^T [b][d][s] ----
__global__ void transpose_v(const float* __restrict__ V, ushort* __restrict__ Vt) {
  __shared__ float T[64][65];
  int bid = blockIdx.x;
  int b  = bid >> 8;
  int st = (bid >> 3) & 31;
  int dt = bid & 7;
  int t  = threadIdx.x;
  int r  = t >> 4, c4 = (t & 15) << 2;
  const float* src = V + ((size_t)b * SDIM + st * 64) * DDIM + dt * 64;
  #pragma unroll
  for (int i = 0; i < 4; ++i) {
    float4 v = *(const float4*)(src + (size_t)(r + i * 16) * DDIM + c4);
    T[r + i * 16][c4 + 0] = v.x; T[r + i * 16][c4 + 1] = v.y;
    T[r + i * 16][c4 + 2] = v.z; T[r + i * 16][c4 + 3] = v.w;
  }
  __syncthreads();
  ushort* dst = Vt + ((size_t)b * DDIM + dt * 64) * SDIM + st * 64;
  #pragma unroll
  for (int i = 0; i < 4; ++i) {
    int dr = r + i * 16;
    ushort4 o;
    o.x = f2bf(T[c4 + 0][dr]); o.y = f2bf(T[c4 + 1][dr]);
    o.z = f2bf(T[c4 + 2][dr]); o.w = f2bf(T[c4 + 3][dr]);
    *(ushort4*)(dst + (size_t)dr * SDIM + c4) = o;
  }
}

// ---- flash attention: QBLK=32, KBLK=32, 4 waves ----
// LDS swizzles:
//  Ksh elem (j,d):  byte = j*1024 + ((d*2) ^ ((j&7)<<4))
//  Vsh elem (d,kk): byte = d*64   + ((kk*2) ^ (((d>>1)&3)<<4))
// both staged via global_load_lds with inverse-swizzled per-lane global src.
__global__ __launch_bounds__(256, 2) void attn(
    const float* __restrict__ Qf, const ushort* __restrict__ Kb,
    const ushort* __restrict__ Vt, float* __restrict__ out) {
  __shared__ __align__(16) char Ksh[32 * 1024];
  __shared__ __align__(16) char Vsh[32 * 1024];
  __shared__ __align__(16) ushort Psh[32 * 40];        // 80 B rows (pad 8 bf16)
  __shared__ float m_s[2][32], l_s[2][32], pmax_s[2][32], psum_s[2][32];

  const int b  = blockIdx.x & 7;                 // batch -> XCD affinity
  const int t  = 63 - (blockIdx.x >> 3);         // descending work order
  const int q0 = t << 5;
  const int tid  = threadIdx.x;
  const int wave = tid >> 6;
  const int lane = tid & 63;
  const int g    = (lane >> 4) & 3;
  const int m16  = lane & 15;
  const int qs   = wave >> 1;                    // q-subtile 0..1
  const int ks   = wave & 1;                     // k-subtile 0..1
  const int dw0  = wave << 7;                    // PV d-slice base (128/wave)

  const ushort* kbb = Kb + (size_t)b * SDIM * DDIM;
  const ushort* vtb = Vt + (size_t)b * DDIM * SDIM;

  // Q fragments: fp32 -> bf16 in-reg, scaled by 1/sqrt(S)
  const float qscale = 0.022097086912079608f;
  bf16x8 qf[16];
  {
    const float* qrow = Qf + ((size_t)b * SDIM + q0 + qs * 16 + m16) * DDIM + g * 8;
    #pragma unroll
    for (int ds = 0; ds < 16; ++ds) {
      float4 u = *(const float4*)(qrow + ds * 32);
      float4 w = *(const float4*)(qrow + ds * 32 + 4);
      union { ushort us[8]; bf16x8 v; } pk;
      pk.us[0] = f2bf(u.x * qscale); pk.us[1] = f2bf(u.y * qscale);
      pk.us[2] = f2bf(u.z * qscale); pk.us[3] = f2bf(u.w * qscale);
      pk.us[4] = f2bf(w.x * qscale); pk.us[5] = f2bf(w.y * qscale);
      pk.us[6] = f2bf(w.z * qscale); pk.us[7] = f2bf(w.w * qscale);
      qf[ds] = pk.v;
    }
  }

  if (tid < 32) { m_s[0][tid] = -1e30f; l_s[0][tid] = 0.0f; }

  const f32x4 zero = {0.f, 0.f, 0.f, 0.f};
  f32x4 acc[2][8];
  #pragma unroll
  for (int qt = 0; qt < 2; ++qt)
    #pragma unroll
    for (int nt = 0; nt < 8; ++nt) acc[qt][nt] = zero;

  const unsigned v_kk = ((lane & 3) ^ ((lane >> 3) & 3)) << 3;  // V stage kk (lane-const)

  // prologue: stage K tile 0
  #pragma unroll
  for (int ji = 0; ji < 8; ++ji) {
    int j = wave * 8 + ji;
    const ushort* src = kbb + (size_t)j * DDIM + ((lane ^ ji) << 3);
    __builtin_amdgcn_global_load_lds((const __attribute__((address_space(1))) void*)src,
        (__attribute__((address_space(3))) void*)(Ksh + j * 1024), 16, 0, 0);
  }

  const int i_row = q0 + qs * 16 + g * 4;
  const int nkt = t + 1;
  for (int kt = 0; kt < nkt; ++kt) {
    const int k0 = kt << 5;
    const int pp = kt & 1;
    __syncthreads();   // [A] Ksh(kt) ready; Vsh free

    // stage V(kt): in flight under QK^T, complete at [B]
    #pragma unroll
    for (int vi = 0; vi < 8; ++vi) {
      int v = wave * 8 + vi;
      const ushort* src = vtb + (size_t)(v * 16 + (lane >> 2)) * SDIM + (k0 + v_kk);
      __builtin_amdgcn_global_load_lds((const __attribute__((address_space(1))) void*)src,
          (__attribute__((address_space(3))) void*)(Vsh + v * 1024), 16, 0, 0);
    }

    // ---- QK^T (two acc chains to halve dependency latency) ----
    f32x4 s0 = zero, s1 = zero;
    const char* kptr = Ksh + (ks * 16 + m16) * 1024;
    const unsigned ksw = (unsigned)((m16 & 7) << 4);
    #pragma unroll
    for (int ds = 0; ds < 16; ds += 2) {
      bf16x8 k0f = *(const bf16x8*)(kptr + (((unsigned)(ds * 64 + g * 16)) ^ ksw));
      s0 = __builtin_amdgcn_mfma_f32_16x16x32_bf16(qf[ds], k0f, s0, 0, 0, 0);
      bf16x8 k1f = *(const bf16x8*)(kptr + (((unsigned)((ds + 1) * 64 + g * 16)) ^ ksw));
      s1 = __builtin_amdgcn_mfma_f32_16x16x32_bf16(qf[ds + 1], k1f, s1, 0, 0, 0);
    }

    const int j_col = k0 + ks * 16 + m16;
    const bool diag = (kt == t);
    float sc[4];
    #pragma unroll
    for (int jj = 0; jj < 4; ++jj) {
      float d = (float)(i_row + jj - j_col);
      float bias = __builtin_amdgcn_rcpf(fmaf(0.2f * d, d, 1.0f));
      float s = s0[jj] + s1[jj] + bias;
      if (diag && (j_col > i_row + jj)) s = -1e30f;
      sc[jj] = s;
    }

    // row max across the 16-lane m16 group
    float rm[4];
    #pragma unroll
    for (int jj = 0; jj < 4; ++jj) {
      float v = sc[jj];
      v = fmaxf(v, __shfl_xor(v, 1));
      v = fmaxf(v, __shfl_xor(v, 2));
      v = fmaxf(v, __shfl_xor(v, 4));
      v = fmaxf(v, __shfl_xor(v, 8));
      rm[jj] = v;
    }
    if (m16 == 0) {
      #pragma unroll
      for (int jj = 0; jj < 4; ++jj) pmax_s[ks][qs * 16 + g * 4 + jj] = rm[jj];
    }

    __syncthreads();   // [B] pmax visible; Ksh reads drained; V(kt) landed

    // stage K(kt+1): in flight under softmax, complete at [D]
    if (kt + 1 < nkt) {
      const int k0n = (kt + 1) << 5;
      #pragma unroll
      for (int ji = 0; ji < 8; ++ji) {
        int j = wave * 8 + ji;
        const ushort* src = kbb + (size_t)(k0n + j) * DDIM + ((lane ^ ji) << 3);
        __builtin_amdgcn_global_load_lds((const __attribute__((address_space(1))) void*)src,
            (__attribute__((address_space(3))) void*)(Ksh + j * 1024), 16, 0, 0);
      }
    }

    // ---- online softmax stats (all waves redundantly, row = lane&31) ----
    const int row = lane & 31;
    float mo = m_s[pp][row];
    float tm = fmaxf(pmax_s[0][row], pmax_s[1][row]);
    bool upd = tm > mo + 8.0f;                   // defer-max THR=8
    float mn = upd ? tm : mo;
    float rr = upd ? __expf(mo - tm) : 1.0f;
    if (wave == 0 && lane < 32) m_s[pp ^ 1][row] = mn;

    float ps[4];
    #pragma unroll
    for (int jj = 0; jj < 4; ++jj) {
      float mq = __shfl(mn, qs * 16 + g * 4 + jj);
      ps[jj] = __expf(sc[jj] - mq);
    }
    #pragma unroll
    for (int jj = 0; jj < 4; ++jj)
      Psh[(qs * 16 + g * 4 + jj) * 40 + ks * 16 + m16] = f2bf(ps[jj]);
    #pragma unroll
    for (int jj = 0; jj < 4; ++jj) {
      float v = ps[jj];
      v += __shfl_xor(v, 1);
      v += __shfl_xor(v, 2);
      v += __shfl_xor(v, 4);
      v += __shfl_xor(v, 8);
      if (m16 == 0) psum_s[ks][qs * 16 + g * 4 + jj] = v;
    }

    // O rescale (skipped when all r==1: defer-max makes this the common case)
    if (!__all(rr == 1.0f)) {
      #pragma unroll
      for (int qt = 0; qt < 2; ++qt)
        #pragma unroll
        for (int jj = 0; jj < 4; ++jj) {
          float r2 = __shfl(rr, qt * 16 + g * 4 + jj);
          #pragma unroll
          for (int nt = 0; nt < 8; ++nt) acc[qt][nt][jj] *= r2;
        }
    }

    __syncthreads();   // [D] Psh+psum visible; K(kt+1) landed

    // ---- PV: O[32 q][128 d-slice] += P[32x32] * V[32 x 128] ----
    bf16x8 pa[2];
    #pragma unroll
    for (int qt = 0; qt < 2; ++qt)
      pa[qt] = *(const bf16x8*)((const char*)Psh + (qt * 16 + m16) * 80 + g * 16);
    #pragma unroll
    for (int nt = 0; nt < 8; ++nt) {
      int d = dw0 + nt * 16 + m16;
      bf16x8 vb = *(const bf16x8*)(Vsh + d * 64 + (((unsigned)(g * 16)) ^ (((d >> 1) & 3) << 4)));
      acc[0][nt] = __builtin_amdgcn_mfma_f32_16x16x32_bf16(pa[0], vb, acc[0][nt], 0, 0, 0);
      acc[1][nt] = __builtin_amdgcn_mfma_f32_16x16x32_bf16(pa[1], vb, acc[1][nt], 0, 0, 0);
    }

    if (wave == 0 && lane < 32)
      l_s[pp ^ 1][row] = l_s[pp][row] * rr + psum_s[0][row] + psum_s[1][row];
  }

  __syncthreads();
  const int pf = nkt & 1;
  #pragma unroll
  for (int qt = 0; qt < 2; ++qt) {
    #pragma unroll
    for (int jj = 0; jj < 4; ++jj) {
      float inv = 1.0f / l_s[pf][qt * 16 + g * 4 + jj];
      float* orow = out + ((size_t)b * SDIM + q0 + qt * 16 + g * 4 + jj) * DDIM + dw0 + m16;
      #pragma unroll
      for (int nt = 0; nt < 8; ++nt)
        orow[nt * 16] = acc[qt][nt][jj] * inv;
    }
  }
}

extern "C" void kernel_launch(void* const* d_in, const int* in_sizes, int n_in,
                              void* d_out, int out_size, void* d_ws, size_t ws_size,
                              hipStream_t stream) {
  const float* Q = (const float*)d_in[0];
  const float* K = (const float*)d_in[1];
  const float* V = (const float*)d_in[2];
  float* out = (float*)d_out;
  ushort* Kb = (ushort*)d_ws;                                  // 16.78 MB
  ushort* Vt = Kb + (size_t)NB * SDIM * DDIM;                  // 16.78 MB
  convert_k<<<1024, 256, 0, stream>>>(K, Kb);
  transpose_v<<<2048, 256, 0, stream>>>(V, Vt);
  attn<<<512, 256, 0, stream>>>(Q, Kb, Vt, out);
}

// Round 3
// 283.272 us; speedup vs baseline: 1.1209x; 1.1209x over previous
//
#include <hip/hip_runtime.h>

#define SDIM 2048
#define DDIM 512
#define NB 8

typedef __bf16 bf16x8 __attribute__((ext_vector_type(8)));
typedef float f32x4 __attribute__((ext_vector_type(4)));

__device__ __forceinline__ ushort f2bf(float f) {
  unsigned u = __float_as_uint(f);
  u = (u + 0x7FFFu + ((u >> 16) & 1u)) >> 16;  // RNE
  return (ushort)u;
}

// ---- prepass: K fp32 -> bf16 ----
__global__ void convert_k(const float* __restrict__ K, ushort* __restrict__ Kb) {
  const long N4 = (long)NB * SDIM * DDIM / 4;
  const long stride = (long)gridDim.x * blockDim.x;
  for (long i = (long)blockIdx.x * blockDim.x + threadIdx.x; i < N4; i += stride) {
    float4 k = ((const float4*)K)[i];
    ushort4 o;
    o.x = f2bf(k.x); o.y = f2bf(k.y); o.z = f2bf(k.z); o.w = f2bf(k.w);
    ((ushort4*)Kb)[i] = o;
  }
}

// ---- prepass: V fp32 [b][s][d] -> bf16 V^T [b][d][s] ----
__global__ void transpose_v(const float* __restrict__ V, ushort* __restrict__ Vt) {
  __shared__ float T[64][65];
  int bid = blockIdx.x;
  int b  = bid >> 8;
  int st = (bid >> 3) & 31;
  int dt = bid & 7;
  int t  = threadIdx.x;
  int r  = t >> 4, c4 = (t & 15) << 2;
  const float* src = V + ((size_t)b * SDIM + st * 64) * DDIM + dt * 64;
  #pragma unroll
  for (int i = 0; i < 4; ++i) {
    float4 v = *(const float4*)(src + (size_t)(r + i * 16) * DDIM + c4);
    T[r + i * 16][c4 + 0] = v.x; T[r + i * 16][c4 + 1] = v.y;
    T[r + i * 16][c4 + 2] = v.z; T[r + i * 16][c4 + 3] = v.w;
  }
  __syncthreads();
  ushort* dst = Vt + ((size_t)b * DDIM + dt * 64) * SDIM + st * 64;
  #pragma unroll
  for (int i = 0; i < 4; ++i) {
    int dr = r + i * 16;
    ushort4 o;
    o.x = f2bf(T[c4 + 0][dr]); o.y = f2bf(T[c4 + 1][dr]);
    o.z = f2bf(T[c4 + 2][dr]); o.w = f2bf(T[c4 + 3][dr]);
    *(ushort4*)(dst + (size_t)dr * SDIM + c4) = o;
  }
}

// ---- flash attention: QBLK=32, KBLK=32, 4 waves ----
// V is NOT LDS-staged (L2-resident; direct per-lane 16B frag loads, issued at
// iteration top for ~900cy slack). K single-buffered in swizzled LDS via
// global_load_lds; raw s_barrier + counted waits so vmcnt never drains
// mid-iteration (stage slack = softmax+PV). Row-sum l comes free from a
// ones-column MFMA accumulator.
__global__ __launch_bounds__(256, 2) void attn(
    const float* __restrict__ Qf, const ushort* __restrict__ Kb,
    const ushort* __restrict__ Vt, float* __restrict__ out) {
  __shared__ __align__(16) char Ksh[32 * 1024];
  __shared__ __align__(16) ushort Psh[32 * 40];        // 80 B rows
  __shared__ float m_s[2][32], pmax_s[2][32];

  // balanced pairing: first 256 blocks take t=63..32 (longest first),
  // next 256 take t=0..31 -> co-resident pair sums ~64 iters constant.
  const int bi   = blockIdx.x;
  const int idx  = bi & 255;
  const int t    = (bi < 256) ? (63 - (idx >> 3)) : (idx >> 3);
  const int b    = idx & 7;                      // batch -> XCD affinity
  const int q0   = t << 5;
  const int tid  = threadIdx.x;
  const int wave = tid >> 6;
  const int lane = tid & 63;
  const int g    = (lane >> 4) & 3;
  const int m16  = lane & 15;
  const int qs   = wave >> 1;                    // q-subtile 0..1
  const int ks   = wave & 1;                     // k-subtile 0..1
  const int dw0  = wave << 7;                    // PV d-slice base (128/wave)

  const ushort* kbb = Kb + (size_t)b * SDIM * DDIM;
  const ushort* vtb = Vt + (size_t)b * DDIM * SDIM;

  // Q fragments: fp32 -> bf16 in-reg, scaled by 1/sqrt(S)
  const float qscale = 0.022097086912079608f;
  bf16x8 qf[16];
  {
    const float* qrow = Qf + ((size_t)b * SDIM + q0 + qs * 16 + m16) * DDIM + g * 8;
    #pragma unroll
    for (int ds = 0; ds < 16; ++ds) {
      float4 u = *(const float4*)(qrow + ds * 32);
      float4 w = *(const float4*)(qrow + ds * 32 + 4);
      union { ushort us[8]; bf16x8 v; } pk;
      pk.us[0] = f2bf(u.x * qscale); pk.us[1] = f2bf(u.y * qscale);
      pk.us[2] = f2bf(u.z * qscale); pk.us[3] = f2bf(u.w * qscale);
      pk.us[4] = f2bf(w.x * qscale); pk.us[5] = f2bf(w.y * qscale);
      pk.us[6] = f2bf(w.z * qscale); pk.us[7] = f2bf(w.w * qscale);
      qf[ds] = pk.v;
    }
  }

  if (tid < 32) m_s[0][tid] = -1e30f;

  union { ushort us[8]; bf16x8 v; } onesu;
  #pragma unroll
  for (int i = 0; i < 8; ++i) onesu.us[i] = 0x3F80;    // bf16 1.0
  const bf16x8 ones = onesu.v;

  const f32x4 zero = {0.f, 0.f, 0.f, 0.f};
  f32x4 acc[2][8];
  f32x4 acc1[2];                                  // ones-column: row sums of P
  #pragma unroll
  for (int qt = 0; qt < 2; ++qt) {
    acc1[qt] = zero;
    #pragma unroll
    for (int nt = 0; nt < 8; ++nt) acc[qt][nt] = zero;
  }

  // prologue: stage K tile 0 (swizzled: byte = j*1024 + ((d*2)^((j&7)<<4)))
  #pragma unroll
  for (int ji = 0; ji < 8; ++ji) {
    int j = wave * 8 + ji;
    const ushort* src = kbb + (size_t)j * DDIM + ((lane ^ ji) << 3);
    __builtin_amdgcn_global_load_lds((const __attribute__((address_space(1))) void*)src,
        (__attribute__((address_space(3))) void*)(Ksh + j * 1024), 16, 0, 0);
  }

  const int i_row = q0 + qs * 16 + g * 4;
  const int nkt = t + 1;
  for (int kt = 0; kt < nkt; ++kt) {
    const int k0 = kt << 5;
    const int pp = kt & 1;
    // [A] K(kt) landed (only K outstanding); LDS quiesced; Psh(prev) consumed
    asm volatile("s_waitcnt vmcnt(0) lgkmcnt(0)" ::: "memory");
    __builtin_amdgcn_s_barrier();

    // V fragments for PV: direct global (L2-hit), full-iteration slack
    bf16x8 vb[8];
    #pragma unroll
    for (int nt = 0; nt < 8; ++nt)
      vb[nt] = *(const bf16x8*)(vtb + (size_t)(dw0 + nt * 16 + m16) * SDIM + k0 + g * 8);

    // ---- QK^T (two acc chains) ----
    f32x4 s0 = zero, s1 = zero;
    const char* kptr = Ksh + (ks * 16 + m16) * 1024;
    const unsigned ksw = (unsigned)((m16 & 7) << 4);
    __builtin_amdgcn_s_setprio(1);
    #pragma unroll
    for (int ds = 0; ds < 16; ds += 2) {
      bf16x8 k0f = *(const bf16x8*)(kptr + (((unsigned)(ds * 64 + g * 16)) ^ ksw));
      s0 = __builtin_amdgcn_mfma_f32_16x16x32_bf16(qf[ds], k0f, s0, 0, 0, 0);
      bf16x8 k1f = *(const bf16x8*)(kptr + (((unsigned)((ds + 1) * 64 + g * 16)) ^ ksw));
      s1 = __builtin_amdgcn_mfma_f32_16x16x32_bf16(qf[ds + 1], k1f, s1, 0, 0, 0);
    }
    __builtin_amdgcn_s_setprio(0);

    const int j_col = k0 + ks * 16 + m16;
    const bool diag = (kt == t);
    float sc[4];
    #pragma unroll
    for (int jj = 0; jj < 4; ++jj) {
      float d = (float)(i_row + jj - j_col);
      float bias = __builtin_amdgcn_rcpf(fmaf(0.2f * d, d, 1.0f));
      float s = s0[jj] + s1[jj] + bias;
      if (diag && (j_col > i_row + jj)) s = -1e30f;
      sc[jj] = s;
    }

    // row max across the 16-lane m16 group
    #pragma unroll
    for (int jj = 0; jj < 4; ++jj) {
      float v = sc[jj];
      v = fmaxf(v, __shfl_xor(v, 1));
      v = fmaxf(v, __shfl_xor(v, 2));
      v = fmaxf(v, __shfl_xor(v, 4));
      v = fmaxf(v, __shfl_xor(v, 8));
      if (m16 == 0) pmax_s[ks][qs * 16 + g * 4 + jj] = v;
    }

    // [B] pmax visible; all waves' Ksh reads retired -> safe to restage
    asm volatile("s_waitcnt lgkmcnt(0)" ::: "memory");
    __builtin_amdgcn_s_barrier();

    // stage K(kt+1): slack = softmax + PV (~800 cy), waited at next [A]
    if (kt + 1 < nkt) {
      const int k0n = (kt + 1) << 5;
      #pragma unroll
      for (int ji = 0; ji < 8; ++ji) {
        int j = wave * 8 + ji;
        const ushort* src = kbb + (size_t)(k0n + j) * DDIM + ((lane ^ ji) << 3);
        __builtin_amdgcn_global_load_lds((const __attribute__((address_space(1))) void*)src,
            (__attribute__((address_space(3))) void*)(Ksh + j * 1024), 16, 0, 0);
      }
    }

    // ---- online softmax (all waves redundantly, row = lane&31) ----
    const int row = lane & 31;
    float mo = m_s[pp][row];
    float tm = fmaxf(pmax_s[0][row], pmax_s[1][row]);
    bool upd = tm > mo + 8.0f;                   // defer-max THR=8
    float mn = upd ? tm : mo;
    float rr = upd ? __expf(mo - tm) : 1.0f;
    if (wave == 0 && lane < 32) m_s[pp ^ 1][row] = mn;

    #pragma unroll
    for (int jj = 0; jj < 4; ++jj) {
      float mq = __shfl(mn, qs * 16 + g * 4 + jj);
      float p = __expf(sc[jj] - mq);
      Psh[(qs * 16 + g * 4 + jj) * 40 + ks * 16 + m16] = f2bf(p);
    }

    // O rescale (defer-max makes skip the common case); ones-acc rescales too
    if (!__all(rr == 1.0f)) {
      #pragma unroll
      for (int qt = 0; qt < 2; ++qt)
        #pragma unroll
        for (int jj = 0; jj < 4; ++jj) {
          float r2 = __shfl(rr, qt * 16 + g * 4 + jj);
          #pragma unroll
          for (int nt = 0; nt < 8; ++nt) acc[qt][nt][jj] *= r2;
          acc1[qt][jj] *= r2;
        }
    }

    // [C] Psh visible
    asm volatile("s_waitcnt lgkmcnt(0)" ::: "memory");
    __builtin_amdgcn_s_barrier();

    // ---- PV: O[32 q][128 d-slice] += P[32x32] * V[32x128]; + ones column ----
    bf16x8 pa[2];
    #pragma unroll
    for (int qt = 0; qt < 2; ++qt)
      pa[qt] = *(const bf16x8*)((const char*)Psh + (qt * 16 + m16) * 80 + g * 16);
    __builtin_amdgcn_s_setprio(1);
    #pragma unroll
    for (int nt = 0; nt < 8; ++nt) {
      acc[0][nt] = __builtin_amdgcn_mfma_f32_16x16x32_bf16(pa[0], vb[nt], acc[0][nt], 0, 0, 0);
      acc[1][nt] = __builtin_amdgcn_mfma_f32_16x16x32_bf16(pa[1], vb[nt], acc[1][nt], 0, 0, 0);
    }
    acc1[0] = __builtin_amdgcn_mfma_f32_16x16x32_bf16(pa[0], ones, acc1[0], 0, 0, 0);
    acc1[1] = __builtin_amdgcn_mfma_f32_16x16x32_bf16(pa[1], ones, acc1[1], 0, 0, 0);
    __builtin_amdgcn_s_setprio(0);
  }

  // epilogue: fully register-resident (l = ones-column accumulator)
  #pragma unroll
  for (int qt = 0; qt < 2; ++qt) {
    #pragma unroll
    for (int jj = 0; jj < 4; ++jj) {
      float inv = 1.0f / acc1[qt][jj];
      float* orow = out + ((size_t)b * SDIM + q0 + qt * 16 + g * 4 + jj) * DDIM + dw0 + m16;
      #pragma unroll
      for (int nt = 0; nt < 8; ++nt)
        orow[nt * 16] = acc[qt][nt][jj] * inv;
    }
  }
}

extern "C" void kernel_launch(void* const* d_in, const int* in_sizes, int n_in,
                              void* d_out, int out_size, void* d_ws, size_t ws_size,
                              hipStream_t stream) {
  const float* Q = (const float*)d_in[0];
  const float* K = (const float*)d_in[1];
  const float* V = (const float*)d_in[2];
  float* out = (float*)d_out;
  ushort* Kb = (ushort*)d_ws;                                  // 16.78 MB
  ushort* Vt = Kb + (size_t)NB * SDIM * DDIM;                  // 16.78 MB
  convert_k<<<2048, 256, 0, stream>>>(K, Kb);
  transpose_v<<<2048, 256, 0, stream>>>(V, Vt);
  attn<<<512, 256, 0, stream>>>(Q, Kb, Vt, out);
}